// Round 13
// baseline (162.854 us; speedup 1.0000x reference)
//
#include <hip/hip_runtime.h>

#define BATCH    1024
#define NUM_VARS 2048
#define LEAVES   (2 * NUM_VARS)              // 4096
#define LEVELS   12
#define WIDTH    4096
#define TOTAL    (LEAVES + LEVELS * WIDTH)   // 53248
#define NWORDS   (TOTAL / 32)                // 1664 bitmask words

#define CAP      1024                        // max active nodes (expect ~150)
#define MAXS     176                         // LDS-resident value slots
#define BSLICE   64                          // batch elems per block
#define NEVB     (BATCH / BSLICE)            // 16 blocks
#define NTHR     1024                        // 16 waves
#define CHUNK    4                           // nodes per wave per gather round

// child code: bits 0..11 = var index (leaf) or slot (node);
//             bit 13 = leaf flag; bit 14 = complement; bit 20 (e.x only) = op.

__device__ __forceinline__ int enc_one(int c, int slot_found)
{
    if (c < NUM_VARS) return c | (1 << 13);
    if (c < LEAVES)   return (c - NUM_VARS) | (1 << 13) | (1 << 14);
    return slot_found;
}

// ---------------------------------------------------------------------------
// Single fused kernel. Each of the 16 blocks:
//   Phase A (mark+build, redundant & deterministic across blocks, all-LDS):
//     backward reachability bitmask -> sorted nid[] -> enc_s records.
//   Phase B (eval): 12 levels; node values in LDS val[MAXS][64]; leaves
//     gathered directly from x; branch-free triple-load child fetch.
// ---------------------------------------------------------------------------
__global__ __launch_bounds__(NTHR, 1)
void circuit_kernel(const float* __restrict__ x,
                    const int4* __restrict__ child4,
                    const int*  __restrict__ op_type,
                    float* __restrict__ spill_all,
                    float* __restrict__ out)
{
    __shared__ int4 enc_s[CAP];               // 16 KB, written Phase A, read B
    __shared__ int  counts_s[LEVELS];
    __shared__ int  lvl_base[LEVELS];
    __shared__ int  total_s;
    __shared__ union {
        struct { unsigned int flg[NWORDS]; int nid[CAP]; } m;   // 10.75 KB (A)
        float val[MAXS][BSLICE];                                 // 44 KB   (B)
    } u;

    const int tid  = threadIdx.x;
    const int lane = tid & 63;
    const int wv   = tid >> 6;                // 0..15

    // ================= Phase A: reachability + record build =================
    for (int i = tid; i < NWORDS; i += NTHR) u.m.flg[i] = 0u;
    __syncthreads();
    if (tid == 0) u.m.flg[NWORDS - 1] = 0x80000000u;      // root = TOTAL-1
    __syncthreads();

    for (int l = LEVELS - 1; l >= 0; --l) {   // backward marking
        const int wbase = 128 * (l + 1);
        #pragma unroll
        for (int j = 0; j < 4; ++j) {
            const int k = (tid << 2) | j;     // node index within level
            if ((u.m.flg[wbase + (k >> 5)] >> (k & 31)) & 1u) {
                const int4 c = child4[l * WIDTH + k];
                atomicOr(&u.m.flg[c.x >> 5], 1u << (c.x & 31));
                atomicOr(&u.m.flg[c.y >> 5], 1u << (c.y & 31));
                atomicOr(&u.m.flg[c.z >> 5], 1u << (c.z & 31));
                atomicOr(&u.m.flg[c.w >> 5], 1u << (c.w & 31));
            }
        }
        __syncthreads();
    }

    // per-level counts (wave wv <-> level wv, parallel)
    if (wv < LEVELS) {
        const unsigned int w0 = u.m.flg[128 * (wv + 1) + 2 * lane];
        const unsigned int w1 = u.m.flg[128 * (wv + 1) + 2 * lane + 1];
        const int pc = __popc(w0) + __popc(w1);
        int scan = pc;
        for (int d = 1; d < 64; d <<= 1) {
            const int up = __shfl_up(scan, d, 64);
            if (lane >= d) scan += up;
        }
        if (lane == 63) counts_s[wv] = scan;
    }
    __syncthreads();
    if (tid == 0) {
        int s = 0;
        for (int l = 0; l < LEVELS; ++l) { lvl_base[l] = s; s += counts_s[l]; }
        total_s = (s < CAP) ? s : CAP;
    }
    __syncthreads();
    if (wv < LEVELS) {                        // write sorted node ids
        const unsigned int w0 = u.m.flg[128 * (wv + 1) + 2 * lane];
        const unsigned int w1 = u.m.flg[128 * (wv + 1) + 2 * lane + 1];
        const int pc = __popc(w0) + __popc(w1);
        int scan = pc;
        for (int d = 1; d < 64; d <<= 1) {
            const int up = __shfl_up(scan, d, 64);
            if (lane >= d) scan += up;
        }
        int base = lvl_base[wv] + scan - pc;
        const int nd0 = LEAVES + wv * WIDTH + 64 * lane;
        unsigned int w = w0;
        while (w) { const int b = __ffs(w) - 1; w &= w - 1;
                    if (base < CAP) u.m.nid[base] = nd0 + b;      base++; }
        w = w1;
        while (w) { const int b = __ffs(w) - 1; w &= w - 1;
                    if (base < CAP) u.m.nid[base] = nd0 + 32 + b; base++; }
    }
    __syncthreads();

    const int S = total_s;
    for (int slot = tid; slot < S; slot += NTHR) {        // one-pass build
        const int nd = u.m.nid[slot];
        const int4 c = child4[nd - LEAVES];
        const int  o = op_type[nd - LEAVES];
        int lo0 = 0, lo1 = 0, lo2 = 0, lo3 = 0;
        int hi0 = S, hi1 = S, hi2 = S, hi3 = S;
        #pragma unroll
        for (int it = 0; it < 10; ++it) {     // 2^10 >= CAP
            const int m0 = (lo0 + hi0) >> 1, m1 = (lo1 + hi1) >> 1;
            const int m2 = (lo2 + hi2) >> 1, m3 = (lo3 + hi3) >> 1;
            const int n0 = u.m.nid[m0], n1 = u.m.nid[m1];
            const int n2 = u.m.nid[m2], n3 = u.m.nid[m3];
            if (lo0 < hi0) { if (n0 < c.x) lo0 = m0 + 1; else hi0 = m0; }
            if (lo1 < hi1) { if (n1 < c.y) lo1 = m1 + 1; else hi1 = m1; }
            if (lo2 < hi2) { if (n2 < c.z) lo2 = m2 + 1; else hi2 = m2; }
            if (lo3 < hi3) { if (n3 < c.w) lo3 = m3 + 1; else hi3 = m3; }
        }
        int4 e;
        e.x = enc_one(c.x, lo0) | (o << 20);
        e.y = enc_one(c.y, lo1);
        e.z = enc_one(c.z, lo2);
        e.w = enc_one(c.w, lo3);
        enc_s[slot] = e;
    }
    __syncthreads();                          // val region may now reuse flg/nid

    // ========================= Phase B: evaluation ==========================
    const int b0 = blockIdx.x * BSLICE;
    const float* xrow = x + (size_t)(b0 + lane) * NUM_VARS;   // this lane's batch row
    float* spill = spill_all + (size_t)blockIdx.x * (CAP - MAXS) * BSLICE;

    int sb = 0;
    for (int l = 0; l < LEVELS; ++l) {
        const int n = counts_s[l];
        for (int i0 = wv * CHUNK; i0 < n; i0 += 16 * CHUNK) {
            int4  ec[CHUNK];
            float v[CHUNK][4];
            // ---- gather: branch-free triple-load, all independent ----
            #pragma unroll
            for (int j = 0; j < CHUNK; ++j) {
                const int i = i0 + j;
                const int slot = sb + ((i < n) ? i : 0);      // clamp tail
                const int4 e = enc_s[slot];
                ec[j] = e;
                #pragma unroll
                for (int k = 0; k < 4; ++k) {
                    const int ee   = (k == 0) ? e.x : (k == 1) ? e.y
                                   : (k == 2) ? e.z : e.w;
                    const int a    = ee & 0xFFF;
                    const int leaf = (ee >> 13) & 1;
                    const int xi = leaf ? a : 0;              // cndmask address
                    const int di = (!leaf && a < MAXS) ? a : 0;
                    const int si = (!leaf && a >= MAXS) ? (a - MAXS) : 0;
                    const float vx = xrow[xi];                // global (x)
                    const float vl = u.val[di][lane];         // LDS
                    const float vs = spill[(size_t)si * BSLICE + lane]; // global
                    float t = leaf ? vx : ((a < MAXS) ? vl : vs);
                    t = (ee & (1 << 14)) ? 1.0f - t : t;      // complement
                    v[j][k] = t;
                }
            }
            // ---- combine + guarded stores ----
            #pragma unroll
            for (int j = 0; j < CHUNK; ++j) {
                const int i = i0 + j;
                const float c0 = v[j][0], c1 = v[j][1], c2 = v[j][2], c3 = v[j][3];
                const float p = ((c0 * c1) * c2) * c3;        // np.prod order
                const float s = ((c0 + c1) + c2) + c3;        // np.sum order
                const float r = (ec[j].x & (1 << 20)) ? s : p;
                if (i < n) {
                    const int slot = sb + i;
                    if (slot < MAXS) u.val[slot][lane] = r;
                    else spill[(size_t)(slot - MAXS) * BSLICE + lane] = r;
                    if (l == LEVELS - 1 && i == n - 1) out[b0 + lane] = r; // root
                }
            }
        }
        __syncthreads();
        sb += n;
    }
}

extern "C" void kernel_launch(void* const* d_in, const int* in_sizes, int n_in,
                              void* d_out, int out_size, void* d_ws, size_t ws_size,
                              hipStream_t stream)
{
    const float* x       = (const float*)d_in[0];
    const int4*  child4  = (const int4*)d_in[1];
    const int*   op_type = (const int*)d_in[2];
    float*       out     = (float*)d_out;
    float*       spill   = (float*)d_ws;      // 16 * 848 * 64 * 4 ≈ 3.5 MB

    circuit_kernel<<<NEVB, NTHR, 0, stream>>>(x, child4, op_type, spill, out);
}

// Round 14
// 98.625 us; speedup vs baseline: 1.6512x; 1.6512x over previous
//
#include <hip/hip_runtime.h>

#define BATCH    1024
#define NUM_VARS 2048
#define LEAVES   (2 * NUM_VARS)              // 4096
#define LEVELS   12
#define WIDTH    4096
#define TOTAL    (LEAVES + LEVELS * WIDTH)   // 53248
#define NWORDS   (TOTAL / 32)                // 1664 bitmask words

#define CAP      1024                        // max active nodes (S~150 verified)
#define BSLICE   64                          // batch elems per eval block
#define NEVB     (BATCH / BSLICE)            // 16 eval blocks
#define ETHR     1024                        // 16 waves per eval block
#define CHUNK    8                           // nodes per wave -> 128/round >= max n

// Value buffer G: rows of 1024 floats. Rows [0,2048) = leaf vars (transposed x).
// Rows [2048, 2048+S) = active-node slots. Child code packing:
//   bits 0..13 : G row index;  bit 14 : complement;  bit 20 (e.x only) : op.

// ---------------------------------------------------------------------------
// Fused setup: blocks 0..511 transpose x into G rows [0,2048);
// block 512 does reachability + record build (independent, overlapped).
// ---------------------------------------------------------------------------
__global__ __launch_bounds__(1024) void setup_kernel(const float* __restrict__ x,
                                                     const int4* __restrict__ child4,
                                                     const int*  __restrict__ op_type,
                                                     float* __restrict__ G,
                                                     int4* __restrict__ enc4,
                                                     int*  __restrict__ counts)
{
    const int tid = threadIdx.x;

    if (blockIdx.x < 512) {
        __shared__ float tile[64][65];
        const int v0 = (blockIdx.x & 31) * 64;
        const int bb = (blockIdx.x >> 5) * 64;
        const int tv = tid & 63;
        const int tb = tid >> 6;              // 0..15
        #pragma unroll
        for (int i = 0; i < 4; ++i) {
            const int bl = tb + i * 16;
            tile[tv][bl] = x[(size_t)(bb + bl) * NUM_VARS + v0 + tv];  // coalesced
        }
        __syncthreads();
        #pragma unroll
        for (int i = 0; i < 4; ++i) {
            const int vl = tb + i * 16;
            G[(size_t)(v0 + vl) * BATCH + bb + tv] = tile[vl][tv];     // coalesced
        }
        return;
    }

    // ---- block 512: reachability + record build ----
    __shared__ unsigned int flg[NWORDS];      // 6.5 KB bitmask
    __shared__ int nid[CAP];                  // sorted active node ids
    __shared__ int lvl_cnt[LEVELS], lvl_base[LEVELS];
    __shared__ int total_s;
    const int lane = tid & 63;
    const int wv   = tid >> 6;                // 0..15

    for (int i = tid; i < NWORDS; i += 1024) flg[i] = 0u;
    __syncthreads();
    if (tid == 0) flg[NWORDS - 1] = 0x80000000u;          // root = TOTAL-1
    __syncthreads();

    for (int l = LEVELS - 1; l >= 0; --l) {   // backward marking
        const int wbase = 128 * (l + 1);
        #pragma unroll
        for (int j = 0; j < 4; ++j) {
            const int k = (tid << 2) | j;
            if ((flg[wbase + (k >> 5)] >> (k & 31)) & 1u) {
                const int4 c = child4[l * WIDTH + k];
                atomicOr(&flg[c.x >> 5], 1u << (c.x & 31));
                atomicOr(&flg[c.y >> 5], 1u << (c.y & 31));
                atomicOr(&flg[c.z >> 5], 1u << (c.z & 31));
                atomicOr(&flg[c.w >> 5], 1u << (c.w & 31));
            }
        }
        __syncthreads();
    }

    if (wv < LEVELS) {                        // parallel per-level counts
        const unsigned int w0 = flg[128 * (wv + 1) + 2 * lane];
        const unsigned int w1 = flg[128 * (wv + 1) + 2 * lane + 1];
        const int pc = __popc(w0) + __popc(w1);
        int scan = pc;
        for (int d = 1; d < 64; d <<= 1) {
            const int up = __shfl_up(scan, d, 64);
            if (lane >= d) scan += up;
        }
        if (lane == 63) lvl_cnt[wv] = scan;
    }
    __syncthreads();
    if (tid == 0) {
        int s = 0;
        for (int l = 0; l < LEVELS; ++l) { lvl_base[l] = s; s += lvl_cnt[l]; }
        total_s = (s < CAP) ? s : CAP;
        for (int l = 0; l < LEVELS; ++l) counts[l] = lvl_cnt[l];
        counts[LEVELS] = total_s;
    }
    __syncthreads();
    if (wv < LEVELS) {                        // write sorted ids
        const unsigned int w0 = flg[128 * (wv + 1) + 2 * lane];
        const unsigned int w1 = flg[128 * (wv + 1) + 2 * lane + 1];
        const int pc = __popc(w0) + __popc(w1);
        int scan = pc;
        for (int d = 1; d < 64; d <<= 1) {
            const int up = __shfl_up(scan, d, 64);
            if (lane >= d) scan += up;
        }
        int base = lvl_base[wv] + scan - pc;
        const int nd0 = LEAVES + wv * WIDTH + 64 * lane;
        unsigned int w = w0;
        while (w) { const int b = __ffs(w) - 1; w &= w - 1;
                    if (base < CAP) nid[base] = nd0 + b;      base++; }
        w = w1;
        while (w) { const int b = __ffs(w) - 1; w &= w - 1;
                    if (base < CAP) nid[base] = nd0 + 32 + b; base++; }
    }
    __syncthreads();

    const int S = total_s;                    // one-pass record build
    for (int slot = tid; slot < S; slot += 1024) {
        const int nd = nid[slot];
        const int4 c = child4[nd - LEAVES];
        const int  o = op_type[nd - LEAVES];
        int lo0 = 0, lo1 = 0, lo2 = 0, lo3 = 0;
        int hi0 = S, hi1 = S, hi2 = S, hi3 = S;
        #pragma unroll
        for (int it = 0; it < 10; ++it) {     // 2^10 >= CAP
            const int m0 = (lo0 + hi0) >> 1, m1 = (lo1 + hi1) >> 1;
            const int m2 = (lo2 + hi2) >> 1, m3 = (lo3 + hi3) >> 1;
            const int n0 = nid[m0], n1 = nid[m1], n2 = nid[m2], n3 = nid[m3];
            if (lo0 < hi0) { if (n0 < c.x) lo0 = m0 + 1; else hi0 = m0; }
            if (lo1 < hi1) { if (n1 < c.y) lo1 = m1 + 1; else hi1 = m1; }
            if (lo2 < hi2) { if (n2 < c.z) lo2 = m2 + 1; else hi2 = m2; }
            if (lo3 < hi3) { if (n3 < c.w) lo3 = m3 + 1; else hi3 = m3; }
        }
        int4 e;
        e.x = (c.x < NUM_VARS) ? c.x : (c.x < LEAVES) ? ((c.x - NUM_VARS) | 0x4000)
                                                      : (NUM_VARS + lo0);
        e.y = (c.y < NUM_VARS) ? c.y : (c.y < LEAVES) ? ((c.y - NUM_VARS) | 0x4000)
                                                      : (NUM_VARS + lo1);
        e.z = (c.z < NUM_VARS) ? c.z : (c.z < LEAVES) ? ((c.z - NUM_VARS) | 0x4000)
                                                      : (NUM_VARS + lo2);
        e.w = (c.w < NUM_VARS) ? c.w : (c.w < LEAVES) ? ((c.w - NUM_VARS) | 0x4000)
                                                      : (NUM_VARS + lo3);
        e.x |= o << 20;
        enc4[slot] = e;
    }
}

// ---------------------------------------------------------------------------
// Evaluation: block b owns batch columns [b*64, b*64+64). 16 waves x CHUNK=8
// nodes -> 128 nodes per gather round >= max level count, so EVERY level is
// one concurrent gather window + one barrier. Loads are a single uniform
// stream G[row*1024+boff] — no branches, no source multiplexing.
// ---------------------------------------------------------------------------
__global__ __launch_bounds__(ETHR, 1) void eval_kernel(float* __restrict__ G,
                                                       const int4* __restrict__ enc4g,
                                                       const int*  __restrict__ countsg,
                                                       float* __restrict__ out)
{
    __shared__ int4 enc_s[CAP];               // 16 KB
    __shared__ int counts_s[LEVELS + 1];
    const int tid  = threadIdx.x;
    const int lane = tid & 63;
    const int wave = tid >> 6;                // 0..15
    const int boff = blockIdx.x * BSLICE + lane;

    if (tid < LEVELS + 1) counts_s[tid] = countsg[tid];
    __syncthreads();
    const int S = counts_s[LEVELS];
    for (int i = tid; i < S; i += ETHR) enc_s[i] = enc4g[i];  // coalesced preload
    __syncthreads();

    int sb = 0;
    for (int l = 0; l < LEVELS; ++l) {
        const int n = counts_s[l];
        for (int i0 = wave * CHUNK; i0 < n; i0 += 16 * CHUNK) {
            int4  ec[CHUNK];
            float v[CHUNK][4];
            // ---- gather: straight-line, all 32 loads independent ----
            #pragma unroll
            for (int j = 0; j < CHUNK; ++j) {
                const int i = i0 + j;
                const int slot = sb + ((i < n) ? i : 0);      // clamp tail, row valid
                const int4 e = enc_s[slot];
                ec[j] = e;
                v[j][0] = G[(size_t)(e.x & 0x3FFF) * BATCH + boff];
                v[j][1] = G[(size_t)(e.y & 0x3FFF) * BATCH + boff];
                v[j][2] = G[(size_t)(e.z & 0x3FFF) * BATCH + boff];
                v[j][3] = G[(size_t)(e.w & 0x3FFF) * BATCH + boff];
            }
            // ---- combine: selects only ----
            #pragma unroll
            for (int j = 0; j < CHUNK; ++j) {
                const int i = i0 + j;
                const int4 e = ec[j];
                const float c0 = (e.x & 0x4000) ? 1.0f - v[j][0] : v[j][0];
                const float c1 = (e.y & 0x4000) ? 1.0f - v[j][1] : v[j][1];
                const float c2 = (e.z & 0x4000) ? 1.0f - v[j][2] : v[j][2];
                const float c3 = (e.w & 0x4000) ? 1.0f - v[j][3] : v[j][3];
                const float p = ((c0 * c1) * c2) * c3;        // np.prod order
                const float s = ((c0 + c1) + c2) + c3;        // np.sum order
                const float r = (e.x & (1 << 20)) ? s : p;
                if (i < n) {
                    G[(size_t)(NUM_VARS + sb + i) * BATCH + boff] = r;
                    if (l == LEVELS - 1 && i == n - 1) out[boff] = r;   // root
                }
            }
        }
        __syncthreads();
        sb += n;
    }
}

extern "C" void kernel_launch(void* const* d_in, const int* in_sizes, int n_in,
                              void* d_out, int out_size, void* d_ws, size_t ws_size,
                              hipStream_t stream)
{
    const float* x       = (const float*)d_in[0];
    const int4*  child4  = (const int4*)d_in[1];
    const int*   op_type = (const int*)d_in[2];
    float*       out     = (float*)d_out;

    char* w = (char*)d_ws;
    float* G      = (float*)w;  w += (size_t)(NUM_VARS + CAP) * BATCH * sizeof(float); // 12.6 MB
    int4*  enc4   = (int4*)w;   w += (size_t)CAP * sizeof(int4);                       // 16 KB
    int*   counts = (int*)w;    w += 64;

    setup_kernel<<<513, 1024, 0, stream>>>(x, child4, op_type, G, enc4, counts);
    eval_kernel<<<NEVB, ETHR, 0, stream>>>(G, enc4, counts, out);
}